// Round 15
// baseline (1019.581 us; speedup 1.0000x reference)
//
#include <hip/hip_runtime.h>
#include <hip/hip_fp16.h>
#include <stdint.h>

typedef _Float16 f16x8 __attribute__((ext_vector_type(8)));
typedef _Float16 f16x4 __attribute__((ext_vector_type(4)));
typedef float    f32x4 __attribute__((ext_vector_type(4)));

static constexpr int NROWS = 32768;   // b*n
static constexpr int NCODE = 8192;
static constexpr int DDIM  = 512;
static constexpr int BM = 128, BN = 256, BK = 64;
static constexpr int NBM = NROWS / BM;    // 256
static constexpr int NBN = NCODE / BN;    // 32
static constexpr int NPART = NBN * 4;     // 128 partials per row (4 qwc strips per bn)

// out layout (floats): quantize [NROWS*DDIM] | embed_ind [NROWS] | dist [NROWS*NCODE]
static constexpr size_t OFF_IND  = (size_t)NROWS * DDIM;
static constexpr size_t OFF_DIST = OFF_IND + NROWS;

// ws layout (bytes)
static constexpr size_t WS_XH   = 0;
static constexpr size_t WS_XL   = WS_XH + (size_t)NROWS * DDIM * 2;
static constexpr size_t WS_EH   = WS_XL + (size_t)NROWS * DDIM * 2;
static constexpr size_t WS_EL   = WS_EH + (size_t)NCODE * DDIM * 2;
static constexpr size_t WS_X2   = WS_EL + (size_t)NCODE * DDIM * 2;
static constexpr size_t WS_E2   = WS_X2 + (size_t)NROWS * 4;
static constexpr size_t WS_PART = WS_E2 + (size_t)NCODE * 4;
// end = WS_PART + NROWS*NPART*8 = 117,604,352 bytes (same as r0 footprint)

__device__ inline void gload_lds16(const void* g, void* l) {
  __builtin_amdgcn_global_load_lds((const __attribute__((address_space(1))) void*)g,
                                   (__attribute__((address_space(3))) void*)l,
                                   16, 0, 0);
}

// ---------- prep: fp32 -> (f16 hi, f16 lo) split + fp64-accumulated norms ----------
__global__ __launch_bounds__(128)
void prep_kernel(const float* __restrict__ x, const float* __restrict__ e,
                 _Float16* __restrict__ xh, _Float16* __restrict__ xl,
                 _Float16* __restrict__ eh, _Float16* __restrict__ el,
                 float* __restrict__ x2, float* __restrict__ e2)
{
  int bid = blockIdx.x;
  const float* src; _Float16 *dh, *dl; float* nrm;
  if (bid < NROWS) {
    src = x + (size_t)bid * DDIM;
    dh = xh + (size_t)bid * DDIM;  dl = xl + (size_t)bid * DDIM;
    nrm = x2 + bid;
  } else {
    int r = bid - NROWS;
    src = e + (size_t)r * DDIM;
    dh = eh + (size_t)r * DDIM;    dl = el + (size_t)r * DDIM;
    nrm = e2 + r;
  }
  int t = threadIdx.x;
  float4 v = reinterpret_cast<const float4*>(src)[t];
  double s = (double)v.x*v.x + (double)v.y*v.y + (double)v.z*v.z + (double)v.w*v.w;
  f16x4 h, l;
  h.x = (_Float16)v.x; l.x = (_Float16)(v.x - (float)h.x);
  h.y = (_Float16)v.y; l.y = (_Float16)(v.y - (float)h.y);
  h.z = (_Float16)v.z; l.z = (_Float16)(v.z - (float)h.z);
  h.w = (_Float16)v.w; l.w = (_Float16)(v.w - (float)h.w);
  reinterpret_cast<f16x4*>(dh)[t] = h;
  reinterpret_cast<f16x4*>(dl)[t] = l;
  #pragma unroll
  for (int m = 1; m < 64; m <<= 1) s += __shfl_xor(s, m);
  __shared__ double sh[2];
  if ((t & 63) == 0) sh[t >> 6] = s;
  __syncthreads();
  if (t == 0) nrm[0] = (float)(sh[0] + sh[1]);
}

// sync helpers
#define BARx __builtin_amdgcn_s_barrier()
#define VMC(n)  asm volatile("s_waitcnt vmcnt(" #n ")" ::: "memory")

// ---------- main: 128x256 tile, single-buffer LDS, 2 blocks/CU for cross-block overlap ----------
// Per block: 8 waves (2 qwr x 4 qwc), wave tile 64x64, acc = 64 VGPR -> fits 128-reg cap
// (__launch_bounds__(512,4) => 4 waves/SIMD = 2 blocks/CU). Single 48 KiB LDS buffer:
//   [tile t in LDS] -> reads+MFMA (2 k-passes, transient frags) -> BAR -> STAGE(t+1) ->
//   VMC(0) -> BAR -> next.
// The per-tile drain stall is covered by the co-resident block's compute phase (m114:
// independent waves co-schedule MFMA and LDS/VMEM pipes fully).
__global__ __launch_bounds__(512, 4)
void dist_gemm_kernel(const _Float16* __restrict__ xh, const _Float16* __restrict__ xl,
                      const _Float16* __restrict__ eh, const _Float16* __restrict__ el,
                      const float* __restrict__ x2, const float* __restrict__ e2,
                      float* __restrict__ dist, float2* __restrict__ part)
{
  __shared__ _Float16 LA[BM * BK];   // 16 KiB
  __shared__ _Float16 LB[BN * BK];   // 32 KiB

  const int tid  = threadIdx.x;
  const int wid  = tid >> 6;
  const int lane = tid & 63;
  const int qwr  = wid >> 2;      // 0..1 : 64-row band
  const int qwc  = wid & 3;       // 0..3 : 64-col strip

  // Locality swizzle: each XCD owns a fixed 4-wide bn strip (2 MB B panel -> L2-resident).
  const int flat = blockIdx.x;
  const int xcd  = flat & 7;
  const int idx  = flat >> 3;          // 0..1023
  const int bn   = xcd * 4 + (idx & 3);
  const int bm   = idx >> 2;           // 0..255
  const int R  = bm * BM;
  const int Cc = bn * BN;

  const int l3 = lane >> 3;
  const int l7 = lane & 7;
  const int srcslot = ((l7 ^ l3) << 4);   // pre-swizzled global 16B-slot (inverse of read swizzle)

  // stage full tile t (A 2 gloads + B 4 gloads per wave) into the single buffer
  auto STAGE = [&](int t) {
    const _Float16* baseA = (t < 16) ? xh : xl;
    const _Float16* baseB = (t < 8 || t >= 16) ? eh : el;
    const int k0b = (t & 7) * (BK * 2);
    #pragma unroll
    for (int i = 0; i < 2; ++i) {
      const int rr = wid * 16 + i * 8;
      gload_lds16((const char*)baseA + (size_t)(R + rr + l3) * (DDIM * 2) + k0b + srcslot,
                  &LA[rr * BK]);
    }
    #pragma unroll
    for (int i = 0; i < 4; ++i) {
      const int rr = wid * 32 + i * 8;
      gload_lds16((const char*)baseB + (size_t)(Cc + rr + l3) * (DDIM * 2) + k0b + srcslot,
                  &LB[rr * BK]);
    }
  };

  const int l15   = lane & 15;
  const int kslot = (lane >> 4) << 4;     // 0,16,32,48 byte k-slot

  auto LDA = [&](f16x8 (&af)[4], int ks) {
    #pragma unroll
    for (int m = 0; m < 4; ++m) {
      const int row = qwr * 64 + m * 16 + l15;
      const int kb  = (ks * 64 + kslot) ^ ((row & 7) << 4);
      af[m] = *(const f16x8*)((const char*)&LA[0] + row * 128 + kb);
    }
  };
  auto LDB = [&](f16x8 (&bf)[4], int ks) {
    #pragma unroll
    for (int n = 0; n < 4; ++n) {
      const int row = qwc * 64 + n * 16 + l15;
      const int kb  = (ks * 64 + kslot) ^ ((row & 7) << 4);
      bf[n] = *(const f16x8*)((const char*)&LB[0] + row * 128 + kb);
    }
  };

  f32x4 acc[4][4] = {};   // 64 accumulator regs

  // prologue: tile 0
  STAGE(0);
  VMC(0);
  BARx;

  for (int t = 0; t < 24; ++t) {
    #pragma unroll
    for (int ks = 0; ks < 2; ++ks) {
      f16x8 af[4], bf[4];           // transient: 32 regs live only within this ks
      LDA(af, ks);
      LDB(bf, ks);
      __builtin_amdgcn_s_setprio(1);
      #pragma unroll
      for (int m = 0; m < 4; ++m)
        #pragma unroll
        for (int n = 0; n < 4; ++n)
          acc[m][n] = __builtin_amdgcn_mfma_f32_16x16x32_f16(af[m], bf[n], acc[m][n], 0, 0, 0);
      __builtin_amdgcn_s_setprio(0);
    }
    BARx;                            // all waves done reading tile t
    if (t < 23) {
      STAGE(t + 1);
      VMC(0);                        // own stores landed...
      BARx;                          // ...and everyone's, before any read
    }
  }

  // ---- epilogue: dist + per-wave per-row argmin ----
  const int q    = lane >> 4;
  const int csub = lane & 15;

  float e2v[4];
  #pragma unroll
  for (int n = 0; n < 4; ++n)
    e2v[n] = e2[Cc + qwc * 64 + n * 16 + csub];

  float bestv[16], besti[16];
  int rix = 0;
  #pragma unroll
  for (int m = 0; m < 4; ++m)
    #pragma unroll
    for (int j = 0; j < 4; ++j, ++rix) {
      const int row = R + qwr * 64 + m * 16 + q * 4 + j;
      const float xv = x2[row];
      float* drow = dist + (size_t)row * NCODE;
      float bv = -3.0e38f, bi = 0.0f;
      #pragma unroll
      for (int n = 0; n < 4; ++n) {
        const int col = Cc + qwc * 64 + n * 16 + csub;
        float xe = acc[m][n][j];
        float d2 = fmaxf((xv + e2v[n]) - 2.0f * xe, 0.0f);
        float dv = -sqrtf(d2);
        drow[col] = dv;
        if (dv > bv) { bv = dv; bi = (float)col; }     // cols ascending => first-max kept
      }
      bestv[rix] = bv;
      besti[rix] = bi;
    }

  // reduce across the 16 lanes sharing each row
  #pragma unroll
  for (int msk = 1; msk < 16; msk <<= 1) {
    #pragma unroll
    for (int r = 0; r < 16; ++r) {
      float ov = __shfl_xor(bestv[r], msk);
      float oi = __shfl_xor(besti[r], msk);
      if (ov > bestv[r] || (ov == bestv[r] && oi < besti[r])) { bestv[r] = ov; besti[r] = oi; }
    }
  }
  if (csub == 0) {
    int rr = 0;
    #pragma unroll
    for (int m = 0; m < 4; ++m)
      #pragma unroll
      for (int j = 0; j < 4; ++j, ++rr) {
        const int row = R + qwr * 64 + m * 16 + q * 4 + j;
        part[(size_t)row * NPART + bn * 4 + qwc] = make_float2(bestv[rr], besti[rr]);
      }
  }
}

// ---------- final: per-row reduce of 128 partials, write index, gather code row ----------
__global__ __launch_bounds__(64)
void reduce_gather_kernel(const float2* __restrict__ part, const float* __restrict__ embed,
                          float* __restrict__ quant, float* __restrict__ ind)
{
  const int row = blockIdx.x;
  const int l = threadIdx.x;
  float2 a = part[(size_t)row * NPART + l];
  float2 b = part[(size_t)row * NPART + 64 + l];
  float bv = a.x, bi = a.y;
  if (b.x > bv || (b.x == bv && b.y < bi)) { bv = b.x; bi = b.y; }
  #pragma unroll
  for (int m = 1; m < 64; m <<= 1) {
    float ov = __shfl_xor(bv, m);
    float oi = __shfl_xor(bi, m);
    if (ov > bv || (ov == bv && oi < bi)) { bv = ov; bi = oi; }
  }
  if (l == 0) ind[row] = bi;
  const int idx = (int)bi;
  const float4* src = reinterpret_cast<const float4*>(embed + (size_t)idx * DDIM);
  float4* dst = reinterpret_cast<float4*>(quant + (size_t)row * DDIM);
  dst[l]      = src[l];
  dst[l + 64] = src[l + 64];
}

extern "C" void kernel_launch(void* const* d_in, const int* in_sizes, int n_in,
                              void* d_out, int out_size, void* d_ws, size_t ws_size,
                              hipStream_t stream) {
  const float* x     = (const float*)d_in[0];
  const float* embed = (const float*)d_in[1];

  char* ws = (char*)d_ws;
  _Float16* xh = (_Float16*)(ws + WS_XH);
  _Float16* xl = (_Float16*)(ws + WS_XL);
  _Float16* eh = (_Float16*)(ws + WS_EH);
  _Float16* el = (_Float16*)(ws + WS_EL);
  float*    x2 = (float*)(ws + WS_X2);
  float*    e2 = (float*)(ws + WS_E2);
  float2*   part = (float2*)(ws + WS_PART);

  float* quant = (float*)d_out;
  float* ind   = (float*)d_out + OFF_IND;
  float* dist  = (float*)d_out + OFF_DIST;

  prep_kernel<<<dim3(NROWS + NCODE), 128, 0, stream>>>(x, embed, xh, xl, eh, el, x2, e2);
  dist_gemm_kernel<<<dim3(NBM * NBN), 512, 0, stream>>>(xh, xl, eh, el, x2, e2, dist, part);
  reduce_gather_kernel<<<dim3(NROWS), 64, 0, stream>>>(part, embed, quant, ind);
}

// Round 16
// 998.480 us; speedup vs baseline: 1.0211x; 1.0211x over previous
//
#include <hip/hip_runtime.h>
#include <hip/hip_fp16.h>
#include <stdint.h>

typedef _Float16 f16x8 __attribute__((ext_vector_type(8)));
typedef _Float16 f16x4 __attribute__((ext_vector_type(4)));
typedef float    f32x4 __attribute__((ext_vector_type(4)));

static constexpr int NROWS = 32768;   // b*n
static constexpr int NCODE = 8192;
static constexpr int DDIM  = 512;
static constexpr int BM = 256, BN = 256, BK = 64;
static constexpr int NBM = NROWS / BM;    // 128
static constexpr int NBN = NCODE / BN;    // 32
static constexpr int NPART = NBN * 2;     // 64 partials per row

// out layout (floats): quantize [NROWS*DDIM] | embed_ind [NROWS] | dist [NROWS*NCODE]
static constexpr size_t OFF_IND  = (size_t)NROWS * DDIM;
static constexpr size_t OFF_DIST = OFF_IND + NROWS;

// ws layout (bytes)
static constexpr size_t WS_XH   = 0;
static constexpr size_t WS_XL   = WS_XH + (size_t)NROWS * DDIM * 2;
static constexpr size_t WS_EH   = WS_XL + (size_t)NROWS * DDIM * 2;
static constexpr size_t WS_EL   = WS_EH + (size_t)NCODE * DDIM * 2;
static constexpr size_t WS_X2   = WS_EL + (size_t)NCODE * DDIM * 2;
static constexpr size_t WS_E2   = WS_X2 + (size_t)NROWS * 4;
static constexpr size_t WS_PART = WS_E2 + (size_t)NCODE * 4;

__device__ inline void gload_lds16(const void* g, void* l) {
  __builtin_amdgcn_global_load_lds((const __attribute__((address_space(1))) void*)g,
                                   (__attribute__((address_space(3))) void*)l,
                                   16, 0, 0);
}

// ---------- prep: fp32 -> (f16 hi, f16 lo) split + fp64-accumulated norms ----------
__global__ __launch_bounds__(128)
void prep_kernel(const float* __restrict__ x, const float* __restrict__ e,
                 _Float16* __restrict__ xh, _Float16* __restrict__ xl,
                 _Float16* __restrict__ eh, _Float16* __restrict__ el,
                 float* __restrict__ x2, float* __restrict__ e2)
{
  int bid = blockIdx.x;
  const float* src; _Float16 *dh, *dl; float* nrm;
  if (bid < NROWS) {
    src = x + (size_t)bid * DDIM;
    dh = xh + (size_t)bid * DDIM;  dl = xl + (size_t)bid * DDIM;
    nrm = x2 + bid;
  } else {
    int r = bid - NROWS;
    src = e + (size_t)r * DDIM;
    dh = eh + (size_t)r * DDIM;    dl = el + (size_t)r * DDIM;
    nrm = e2 + r;
  }
  int t = threadIdx.x;
  float4 v = reinterpret_cast<const float4*>(src)[t];
  double s = (double)v.x*v.x + (double)v.y*v.y + (double)v.z*v.z + (double)v.w*v.w;
  f16x4 h, l;
  h.x = (_Float16)v.x; l.x = (_Float16)(v.x - (float)h.x);
  h.y = (_Float16)v.y; l.y = (_Float16)(v.y - (float)h.y);
  h.z = (_Float16)v.z; l.z = (_Float16)(v.z - (float)h.z);
  h.w = (_Float16)v.w; l.w = (_Float16)(v.w - (float)h.w);
  reinterpret_cast<f16x4*>(dh)[t] = h;
  reinterpret_cast<f16x4*>(dl)[t] = l;
  #pragma unroll
  for (int m = 1; m < 64; m <<= 1) s += __shfl_xor(s, m);
  __shared__ double sh[2];
  if ((t & 63) == 0) sh[t >> 6] = s;
  __syncthreads();
  if (t == 0) nrm[0] = (float)(sh[0] + sh[1]);
}

// sync helpers
#define BARx __builtin_amdgcn_s_barrier()
#define VMC(n)  asm volatile("s_waitcnt vmcnt(" #n ")" ::: "memory")
#define LGK0 do { asm volatile("s_waitcnt lgkmcnt(0)" ::: "memory"); \
                  __builtin_amdgcn_sched_barrier(0); } while (0)

// 16-MFMA cluster, forced inline so array refs dissolve
__device__ __forceinline__ void MMX(f32x4 (&ac)[2][4], const f16x8 (&af)[2][2],
                                    const f16x8 (&bf)[4][2]) {
  __builtin_amdgcn_s_setprio(1);
  #pragma unroll
  for (int m = 0; m < 2; ++m)
    #pragma unroll
    for (int n = 0; n < 4; ++n)
      #pragma unroll
      for (int ks = 0; ks < 2; ++ks)
        ac[m][n] = __builtin_amdgcn_mfma_f32_16x16x32_f16(af[m][ks], bf[n][ks], ac[m][n], 0, 0, 0);
  __builtin_amdgcn_s_setprio(0);
}

// ---------- main: 256x256 4-phase/tile with the m201 MFMA sandwich ----------
// Identical staging stream / vmcnt ledger / reads as the verified r13 kernel.
// Phase shape (m201 template): {reads (data confirmed >=1 barrier ago); stage; vmcnt} ->
// BARRIER -> lgkmcnt(0)+sched_barrier(0) -> setprio(1); 16 MFMA; setprio(0) -> BARRIER.
// Draining lgkm BEFORE the cluster keeps each 16-MFMA burst uninterrupted, so the two
// waves per SIMD alternate clean bursts instead of stalling mid-cluster in lockstep.
__global__ __launch_bounds__(512, 1)
void dist_gemm_kernel(const _Float16* __restrict__ xh, const _Float16* __restrict__ xl,
                      const _Float16* __restrict__ eh, const _Float16* __restrict__ el,
                      const float* __restrict__ x2, const float* __restrict__ e2,
                      float* __restrict__ dist, float2* __restrict__ part)
{
  __shared__ _Float16 L[2][2][BM * BK];   // [buf][A=0/B=1][256*64] = 128 KiB

  const int tid  = threadIdx.x;
  const int wid  = tid >> 6;
  const int lane = tid & 63;
  const int qwr  = wid >> 1;      // 0..3 : 32-row band within each 128-row half
  const int qwc  = wid & 1;       // 0..1 : 64-col half within each 128-col half

  // Locality swizzle: each XCD owns a fixed 4-wide bn strip (2 MB B panel -> L2-resident).
  const int flat = blockIdx.x;
  const int xcd  = flat & 7;
  const int idx  = flat >> 3;          // 0..511
  const int bn   = xcd * 4 + (idx & 3);
  const int bm   = idx >> 2;           // 0..127
  const int R  = bm * BM;
  const int Cc = bn * BN;

  const int l3 = lane >> 3;
  const int l7 = lane & 7;
  const int srcslot = ((l7 ^ l3) << 4);   // pre-swizzled global 16B-slot (inverse of read swizzle)

  auto STAGE_HALF = [&](int t, int nb, int half) {
    const int ab = half & 1;
    const int hh = half >> 1;
    const _Float16* base;
    size_t rowbase;
    if (ab == 0) { base = (t < 16) ? xh : xl;              rowbase = (size_t)R;  }
    else         { base = (t < 8 || t >= 16) ? eh : el;    rowbase = (size_t)Cc; }
    const int k0b = (t & 7) * (BK * 2);
    #pragma unroll
    for (int i = 0; i < 2; ++i) {
      const int rr = hh * 128 + wid * 16 + i * 8;
      gload_lds16((const char*)base + (rowbase + rr + l3) * (DDIM * 2) + k0b + srcslot,
                  &L[nb][ab][rr * BK]);
    }
  };

  const int l15   = lane & 15;
  const int kslot = (lane >> 4) << 4;     // 0,16,32,48 byte k-slot

  auto LDA = [&](f16x8 (&af)[2][2], int b, int mq) {
    #pragma unroll
    for (int m = 0; m < 2; ++m)
      #pragma unroll
      for (int ks = 0; ks < 2; ++ks) {
        const int row = mq * 128 + qwr * 32 + m * 16 + l15;
        const int kb  = (ks * 64 + kslot) ^ ((row & 7) << 4);
        af[m][ks] = *(const f16x8*)((const char*)&L[b][0][0] + row * 128 + kb);
      }
  };
  auto LDB = [&](f16x8 (&bf)[4][2], int b, int nq) {
    #pragma unroll
    for (int n = 0; n < 4; ++n)
      #pragma unroll
      for (int ks = 0; ks < 2; ++ks) {
        const int row = nq * 128 + qwc * 64 + n * 16 + l15;
        const int kb  = (ks * 64 + kslot) ^ ((row & 7) << 4);
        bf[n][ks] = *(const f16x8*)((const char*)&L[b][1][0] + row * 128 + kb);
      }
  };

  f32x4 acc[2][2][2][4] = {};   // [mq][nq][m][n] = 128 accumulator regs

  // prologue: h0..h3(0)->buf0, h0(1)->buf1 = 10 vmem ops; VMC(6) retires h0,h1(0).
  STAGE_HALF(0, 0, 0);
  STAGE_HALF(0, 0, 1);
  STAGE_HALF(0, 0, 2);
  STAGE_HALF(0, 0, 3);
  STAGE_HALF(1, 1, 0);
  VMC(6);
  BARx;

  for (int t = 0; t < 22; ++t) {
    const int b = t & 1;
    f16x8 af0[2][2], af1[2][2], bf0[4][2], bf1[4][2];

    // p1: reads h0,h1(t) [retired @p4(t-1)/prologue]; stage h1(t+1); MFMA q00
    LDA(af0, b, 0);
    LDB(bf0, b, 0);
    STAGE_HALF(t + 1, b ^ 1, 1);
    VMC(6);  BARx;                      // retires h2(t)
    LGK0;
    MMX(acc[0][0], af0, bf0);
    BARx;

    // p2: read h2(t) [retired @p1]; stage h2(t+1); MFMA q10
    LDA(af1, b, 1);
    STAGE_HALF(t + 1, b ^ 1, 2);
    VMC(6);  BARx;                      // retires h3(t)
    LGK0;
    MMX(acc[1][0], af1, bf0);
    BARx;

    // p3: read h3(t) [retired @p2]; stage h3(t+1); MFMA q11
    LDB(bf1, b, 1);
    STAGE_HALF(t + 1, b ^ 1, 3);
    BARx;
    LGK0;
    MMX(acc[1][1], af1, bf1);
    BARx;

    // p4: no reads; stage h0(t+2) into current buf (region last read @p1, >=3 barriers ago)
    STAGE_HALF(t + 2, b, 0);
    VMC(6);  BARx;                      // retires h0(t+1),h1(t+1)
    MMX(acc[0][1], af0, bf1);
    BARx;
  }

  // ---- peeled tile 22 (buf0): stages only h1..h3(23) ----
  {
    f16x8 af0[2][2], af1[2][2], bf0[4][2], bf1[4][2];
    LDA(af0, 0, 0);
    LDB(bf0, 0, 0);
    STAGE_HALF(23, 1, 1);
    VMC(6);  BARx;
    LGK0;
    MMX(acc[0][0], af0, bf0);
    BARx;
    LDA(af1, 0, 1);
    STAGE_HALF(23, 1, 2);
    VMC(6);  BARx;
    LGK0;
    MMX(acc[1][0], af1, bf0);
    BARx;
    LDB(bf1, 0, 1);
    STAGE_HALF(23, 1, 3);
    BARx;
    LGK0;
    MMX(acc[1][1], af1, bf1);
    BARx;
    VMC(4);  BARx;                      // retires h0(23),h1(23)
    MMX(acc[0][1], af0, bf1);
    BARx;
  }
  // ---- peeled tile 23 (buf1): drain ----
  {
    f16x8 af0[2][2], af1[2][2], bf0[4][2], bf1[4][2];
    LDA(af0, 1, 0);
    LDB(bf0, 1, 0);
    VMC(2);  BARx;                      // retires h2(23)
    LDA(af1, 1, 1);
    LGK0;
    MMX(acc[0][0], af0, bf0);
    MMX(acc[1][0], af1, bf0);
    VMC(0);  BARx;                      // retires h3(23)
    LDB(bf1, 1, 1);
    LGK0;
    MMX(acc[1][1], af1, bf1);
    MMX(acc[0][1], af0, bf1);
  }

  // ---- epilogue: dist + per-wave per-row argmin ----
  const int q    = lane >> 4;
  const int csub = lane & 15;

  float e2v[2][4];
  #pragma unroll
  for (int nq = 0; nq < 2; ++nq)
    #pragma unroll
    for (int n = 0; n < 4; ++n)
      e2v[nq][n] = e2[Cc + nq * 128 + qwc * 64 + n * 16 + csub];

  float bestv[16], besti[16];
  int rix = 0;
  #pragma unroll
  for (int mq = 0; mq < 2; ++mq)
    #pragma unroll
    for (int m = 0; m < 2; ++m)
      #pragma unroll
      for (int j = 0; j < 4; ++j, ++rix) {
        const int row = R + mq * 128 + qwr * 32 + m * 16 + q * 4 + j;
        const float xv = x2[row];
        float* drow = dist + (size_t)row * NCODE;
        float bv = -3.0e38f, bi = 0.0f;
        #pragma unroll
        for (int nq = 0; nq < 2; ++nq)
          #pragma unroll
          for (int n = 0; n < 4; ++n) {
            const int col = Cc + nq * 128 + qwc * 64 + n * 16 + csub;
            float xe = acc[mq][nq][m][n][j];
            float d2 = fmaxf((xv + e2v[nq][n]) - 2.0f * xe, 0.0f);
            float dv = -sqrtf(d2);
            drow[col] = dv;
            if (dv > bv) { bv = dv; bi = (float)col; }     // cols ascending => first-max kept
          }
        bestv[rix] = bv;
        besti[rix] = bi;
      }

  // reduce across the 16 lanes sharing each row
  #pragma unroll
  for (int msk = 1; msk < 16; msk <<= 1) {
    #pragma unroll
    for (int r = 0; r < 16; ++r) {
      float ov = __shfl_xor(bestv[r], msk);
      float oi = __shfl_xor(besti[r], msk);
      if (ov > bestv[r] || (ov == bestv[r] && oi < besti[r])) { bestv[r] = ov; besti[r] = oi; }
    }
  }
  if (csub == 0) {
    int rr = 0;
    #pragma unroll
    for (int mq = 0; mq < 2; ++mq)
      #pragma unroll
      for (int m = 0; m < 2; ++m)
        #pragma unroll
        for (int j = 0; j < 4; ++j, ++rr) {
          const int row = R + mq * 128 + qwr * 32 + m * 16 + q * 4 + j;
          part[(size_t)row * NPART + bn * 2 + qwc] = make_float2(bestv[rr], besti[rr]);
        }
  }
}

// ---------- final: per-row reduce of 64 partials, write index, gather code row ----------
__global__ __launch_bounds__(64)
void reduce_gather_kernel(const float2* __restrict__ part, const float* __restrict__ embed,
                          float* __restrict__ quant, float* __restrict__ ind)
{
  const int row = blockIdx.x;
  const int l = threadIdx.x;
  float2 a = part[(size_t)row * NPART + l];
  float bv = a.x, bi = a.y;
  #pragma unroll
  for (int m = 1; m < 64; m <<= 1) {
    float ov = __shfl_xor(bv, m);
    float oi = __shfl_xor(bi, m);
    if (ov > bv || (ov == bv && oi < bi)) { bv = ov; bi = oi; }
  }
  if (l == 0) ind[row] = bi;
  const int idx = (int)bi;
  const float4* src = reinterpret_cast<const float4*>(embed + (size_t)idx * DDIM);
  float4* dst = reinterpret_cast<float4*>(quant + (size_t)row * DDIM);
  dst[l]      = src[l];
  dst[l + 64] = src[l + 64];
}

extern "C" void kernel_launch(void* const* d_in, const int* in_sizes, int n_in,
                              void* d_out, int out_size, void* d_ws, size_t ws_size,
                              hipStream_t stream) {
  const float* x     = (const float*)d_in[0];
  const float* embed = (const float*)d_in[1];

  char* ws = (char*)d_ws;
  _Float16* xh = (_Float16*)(ws + WS_XH);
  _Float16* xl = (_Float16*)(ws + WS_XL);
  _Float16* eh = (_Float16*)(ws + WS_EH);
  _Float16* el = (_Float16*)(ws + WS_EL);
  float*    x2 = (float*)(ws + WS_X2);
  float*    e2 = (float*)(ws + WS_E2);
  float2*   part = (float2*)(ws + WS_PART);

  float* quant = (float*)d_out;
  float* ind   = (float*)d_out + OFF_IND;
  float* dist  = (float*)d_out + OFF_DIST;

  prep_kernel<<<dim3(NROWS + NCODE), 128, 0, stream>>>(x, embed, xh, xl, eh, el, x2, e2);
  dist_gemm_kernel<<<dim3(NBM * NBN), 512, 0, stream>>>(xh, xl, eh, el, x2, e2, dist, part);
  reduce_gather_kernel<<<dim3(NROWS), 64, 0, stream>>>(part, embed, quant, ind);
}

// Round 17
// 949.393 us; speedup vs baseline: 1.0739x; 1.0517x over previous
//
#include <hip/hip_runtime.h>
#include <hip/hip_fp16.h>
#include <stdint.h>

typedef _Float16 f16x8 __attribute__((ext_vector_type(8)));
typedef _Float16 f16x4 __attribute__((ext_vector_type(4)));
typedef float    f32x4 __attribute__((ext_vector_type(4)));

static constexpr int NROWS = 32768;   // b*n
static constexpr int NCODE = 8192;
static constexpr int DDIM  = 512;
static constexpr int BM = 256, BN = 256, BK = 64;
static constexpr int NBM = NROWS / BM;    // 128
static constexpr int NBN = NCODE / BN;    // 32
static constexpr int NPART = NBN * 2;     // 64 partials per row

// out layout (floats): quantize [NROWS*DDIM] | embed_ind [NROWS] | dist [NROWS*NCODE]
static constexpr size_t OFF_IND  = (size_t)NROWS * DDIM;
static constexpr size_t OFF_DIST = OFF_IND + NROWS;

// ws layout (bytes)
static constexpr size_t WS_XH   = 0;
static constexpr size_t WS_XL   = WS_XH + (size_t)NROWS * DDIM * 2;
static constexpr size_t WS_EH   = WS_XL + (size_t)NROWS * DDIM * 2;
static constexpr size_t WS_EL   = WS_EH + (size_t)NCODE * DDIM * 2;
static constexpr size_t WS_X2   = WS_EL + (size_t)NCODE * DDIM * 2;
static constexpr size_t WS_E2   = WS_X2 + (size_t)NROWS * 4;
static constexpr size_t WS_PART = WS_E2 + (size_t)NCODE * 4;

__device__ inline void gload_lds16(const void* g, void* l) {
  __builtin_amdgcn_global_load_lds((const __attribute__((address_space(1))) void*)g,
                                   (__attribute__((address_space(3))) void*)l,
                                   16, 0, 0);
}

// ---------- prep: fp32 -> (f16 hi, f16 lo) split + fp64-accumulated norms ----------
__global__ __launch_bounds__(128)
void prep_kernel(const float* __restrict__ x, const float* __restrict__ e,
                 _Float16* __restrict__ xh, _Float16* __restrict__ xl,
                 _Float16* __restrict__ eh, _Float16* __restrict__ el,
                 float* __restrict__ x2, float* __restrict__ e2)
{
  int bid = blockIdx.x;
  const float* src; _Float16 *dh, *dl; float* nrm;
  if (bid < NROWS) {
    src = x + (size_t)bid * DDIM;
    dh = xh + (size_t)bid * DDIM;  dl = xl + (size_t)bid * DDIM;
    nrm = x2 + bid;
  } else {
    int r = bid - NROWS;
    src = e + (size_t)r * DDIM;
    dh = eh + (size_t)r * DDIM;    dl = el + (size_t)r * DDIM;
    nrm = e2 + r;
  }
  int t = threadIdx.x;
  float4 v = reinterpret_cast<const float4*>(src)[t];
  double s = (double)v.x*v.x + (double)v.y*v.y + (double)v.z*v.z + (double)v.w*v.w;
  f16x4 h, l;
  h.x = (_Float16)v.x; l.x = (_Float16)(v.x - (float)h.x);
  h.y = (_Float16)v.y; l.y = (_Float16)(v.y - (float)h.y);
  h.z = (_Float16)v.z; l.z = (_Float16)(v.z - (float)h.z);
  h.w = (_Float16)v.w; l.w = (_Float16)(v.w - (float)h.w);
  reinterpret_cast<f16x4*>(dh)[t] = h;
  reinterpret_cast<f16x4*>(dl)[t] = l;
  #pragma unroll
  for (int m = 1; m < 64; m <<= 1) s += __shfl_xor(s, m);
  __shared__ double sh[2];
  if ((t & 63) == 0) sh[t >> 6] = s;
  __syncthreads();
  if (t == 0) nrm[0] = (float)(sh[0] + sh[1]);
}

// sync helpers
#define BARx __builtin_amdgcn_s_barrier()
#define VMC(n)  asm volatile("s_waitcnt vmcnt(" #n ")" ::: "memory")

// 16-MFMA cluster, forced inline so array refs dissolve
__device__ __forceinline__ void MMX(f32x4 (&ac)[2][4], const f16x8 (&af)[2][2],
                                    const f16x8 (&bf)[4][2]) {
  __builtin_amdgcn_s_setprio(1);
  #pragma unroll
  for (int m = 0; m < 2; ++m)
    #pragma unroll
    for (int n = 0; n < 4; ++n)
      #pragma unroll
      for (int ks = 0; ks < 2; ++ks)
        ac[m][n] = __builtin_amdgcn_mfma_f32_16x16x32_f16(af[m][ks], bf[n][ks], ac[m][n], 0, 0, 0);
  __builtin_amdgcn_s_setprio(0);
}

// ---------- main: 256x256 4-phase/tile, m201-ordered (reads PRE-barrier) split-GEMM ----------
// Halves: h0=A rows0-127, h1=B rows0-127, h2=A rows128-255, h3=B rows128-255 (2 gloads/wave each).
// Stage stream: p1:h1(t+1) p2:h2(t+1) p3:h3(t+1) p4:h0(t+2).  vmcnt(6) at p1,p2,p4; none at p3.
// Phase order: ds_read frags for THIS phase (data retired >=1 barrier ago) -> stage ->
// vmcnt -> barrier -> MFMA.  Reads fly during barrier-wait and under other waves' MFMAs;
// frag live ranges end at the same phase's MFMA (no cross-tile carrying -> no register cliff).
// Retirement proof (FIFO, steady state Q entering p1 = [h2(t),h3(t),h0(t+1)] = 6):
//   p1 reads h0,h1(t): retired @p4(t-1) VMC(6)+bar.  p2 reads h2(t): @p1 VMC(6)+bar.
//   p3 reads h3(t): @p2 VMC(6)+bar.  p4: no reads.
__global__ __launch_bounds__(512, 1)
void dist_gemm_kernel(const _Float16* __restrict__ xh, const _Float16* __restrict__ xl,
                      const _Float16* __restrict__ eh, const _Float16* __restrict__ el,
                      const float* __restrict__ x2, const float* __restrict__ e2,
                      float* __restrict__ dist, float2* __restrict__ part)
{
  __shared__ _Float16 L[2][2][BM * BK];   // [buf][A=0/B=1][256*64] = 128 KiB

  const int tid  = threadIdx.x;
  const int wid  = tid >> 6;
  const int lane = tid & 63;
  const int qwr  = wid >> 1;      // 0..3 : 32-row band within each 128-row half
  const int qwc  = wid & 1;       // 0..1 : 64-col half within each 128-col half

  // Locality swizzle: each XCD owns a fixed 4-wide bn strip (2 MB B panel -> L2-resident).
  const int flat = blockIdx.x;
  const int xcd  = flat & 7;
  const int idx  = flat >> 3;          // 0..511
  const int bn   = xcd * 4 + (idx & 3);
  const int bm   = idx >> 2;           // 0..127
  const int R  = bm * BM;
  const int Cc = bn * BN;

  const int l3 = lane >> 3;
  const int l7 = lane & 7;
  const int srcslot = ((l7 ^ l3) << 4);   // pre-swizzled global 16B-slot (inverse of read swizzle)

  auto STAGE_HALF = [&](int t, int nb, int half) {
    const int ab = half & 1;
    const int hh = half >> 1;
    const _Float16* base;
    size_t rowbase;
    if (ab == 0) { base = (t < 16) ? xh : xl;              rowbase = (size_t)R;  }
    else         { base = (t < 8 || t >= 16) ? eh : el;    rowbase = (size_t)Cc; }
    const int k0b = (t & 7) * (BK * 2);
    #pragma unroll
    for (int i = 0; i < 2; ++i) {
      const int rr = hh * 128 + wid * 16 + i * 8;
      gload_lds16((const char*)base + (rowbase + rr + l3) * (DDIM * 2) + k0b + srcslot,
                  &L[nb][ab][rr * BK]);
    }
  };

  const int l15   = lane & 15;
  const int kslot = (lane >> 4) << 4;     // 0,16,32,48 byte k-slot

  auto LDA = [&](f16x8 (&af)[2][2], int b, int mq) {
    #pragma unroll
    for (int m = 0; m < 2; ++m)
      #pragma unroll
      for (int ks = 0; ks < 2; ++ks) {
        const int row = mq * 128 + qwr * 32 + m * 16 + l15;
        const int kb  = (ks * 64 + kslot) ^ ((row & 7) << 4);
        af[m][ks] = *(const f16x8*)((const char*)&L[b][0][0] + row * 128 + kb);
      }
  };
  auto LDB = [&](f16x8 (&bf)[4][2], int b, int nq) {
    #pragma unroll
    for (int n = 0; n < 4; ++n)
      #pragma unroll
      for (int ks = 0; ks < 2; ++ks) {
        const int row = nq * 128 + qwc * 64 + n * 16 + l15;
        const int kb  = (ks * 64 + kslot) ^ ((row & 7) << 4);
        bf[n][ks] = *(const f16x8*)((const char*)&L[b][1][0] + row * 128 + kb);
      }
  };

  f32x4 acc[2][2][2][4] = {};   // [mq][nq][m][n] = 128 accumulator regs

  // prologue: h0..h3(0)->buf0, h0(1)->buf1 = 10 vmem ops; VMC(6) retires h0,h1(0).
  STAGE_HALF(0, 0, 0);
  STAGE_HALF(0, 0, 1);
  STAGE_HALF(0, 0, 2);
  STAGE_HALF(0, 0, 3);
  STAGE_HALF(1, 1, 0);
  VMC(6);
  BARx;

  for (int t = 0; t < 22; ++t) {
    const int b = t & 1;
    f16x8 af0[2][2], af1[2][2], bf0[4][2], bf1[4][2];

    // p1: reads h0,h1(t) [retired @p4(t-1)/prologue] PRE-barrier; stage h1(t+1); MFMA q00
    LDA(af0, b, 0);
    LDB(bf0, b, 0);
    STAGE_HALF(t + 1, b ^ 1, 1);
    VMC(6);  BARx;                      // retires h2(t)
    MMX(acc[0][0], af0, bf0);

    // p2: read h2(t) [retired @p1] PRE-barrier; stage h2(t+1); MFMA q10
    LDA(af1, b, 1);
    STAGE_HALF(t + 1, b ^ 1, 2);
    VMC(6);  BARx;                      // retires h3(t)
    MMX(acc[1][0], af1, bf0);

    // p3: read h3(t) [retired @p2] PRE-barrier; stage h3(t+1); MFMA q11
    LDB(bf1, b, 1);
    STAGE_HALF(t + 1, b ^ 1, 3);
    BARx;
    MMX(acc[1][1], af1, bf1);

    // p4: no reads; stage h0(t+2) into current buf (region last read @p1, 3 barriers ago)
    STAGE_HALF(t + 2, b, 0);
    VMC(6);  BARx;                      // retires h0(t+1),h1(t+1)
    MMX(acc[0][1], af0, bf1);
  }

  // ---- peeled tile 22 (buf0): stages only h1..h3(23) ----
  {
    f16x8 af0[2][2], af1[2][2], bf0[4][2], bf1[4][2];
    LDA(af0, 0, 0);
    LDB(bf0, 0, 0);
    STAGE_HALF(23, 1, 1);
    VMC(6);  BARx;
    MMX(acc[0][0], af0, bf0);
    LDA(af1, 0, 1);
    STAGE_HALF(23, 1, 2);
    VMC(6);  BARx;
    MMX(acc[1][0], af1, bf0);
    LDB(bf1, 0, 1);
    STAGE_HALF(23, 1, 3);
    BARx;
    MMX(acc[1][1], af1, bf1);
    VMC(4);  BARx;                      // retires h0(23),h1(23)
    MMX(acc[0][1], af0, bf1);
  }
  // ---- peeled tile 23 (buf1): drain ----
  {
    f16x8 af0[2][2], af1[2][2], bf0[4][2], bf1[4][2];
    LDA(af0, 1, 0);
    LDB(bf0, 1, 0);
    VMC(2);  BARx;                      // retires h2(23)
    LDA(af1, 1, 1);
    MMX(acc[0][0], af0, bf0);
    MMX(acc[1][0], af1, bf0);
    VMC(0);  BARx;                      // retires h3(23)
    LDB(bf1, 1, 1);
    MMX(acc[1][1], af1, bf1);
    MMX(acc[0][1], af0, bf1);
  }

  // ---- epilogue: dist + per-wave per-row argmin ----
  const int q    = lane >> 4;
  const int csub = lane & 15;

  float e2v[2][4];
  #pragma unroll
  for (int nq = 0; nq < 2; ++nq)
    #pragma unroll
    for (int n = 0; n < 4; ++n)
      e2v[nq][n] = e2[Cc + nq * 128 + qwc * 64 + n * 16 + csub];

  float bestv[16], besti[16];
  int rix = 0;
  #pragma unroll
  for (int mq = 0; mq < 2; ++mq)
    #pragma unroll
    for (int m = 0; m < 2; ++m)
      #pragma unroll
      for (int j = 0; j < 4; ++j, ++rix) {
        const int row = R + mq * 128 + qwr * 32 + m * 16 + q * 4 + j;
        const float xv = x2[row];
        float* drow = dist + (size_t)row * NCODE;
        float bv = -3.0e38f, bi = 0.0f;
        #pragma unroll
        for (int nq = 0; nq < 2; ++nq)
          #pragma unroll
          for (int n = 0; n < 4; ++n) {
            const int col = Cc + nq * 128 + qwc * 64 + n * 16 + csub;
            float xe = acc[mq][nq][m][n][j];
            float d2 = fmaxf((xv + e2v[nq][n]) - 2.0f * xe, 0.0f);
            float dv = -sqrtf(d2);
            drow[col] = dv;
            if (dv > bv) { bv = dv; bi = (float)col; }     // cols ascending => first-max kept
          }
        bestv[rix] = bv;
        besti[rix] = bi;
      }

  // reduce across the 16 lanes sharing each row
  #pragma unroll
  for (int msk = 1; msk < 16; msk <<= 1) {
    #pragma unroll
    for (int r = 0; r < 16; ++r) {
      float ov = __shfl_xor(bestv[r], msk);
      float oi = __shfl_xor(besti[r], msk);
      if (ov > bestv[r] || (ov == bestv[r] && oi < besti[r])) { bestv[r] = ov; besti[r] = oi; }
    }
  }
  if (csub == 0) {
    int rr = 0;
    #pragma unroll
    for (int mq = 0; mq < 2; ++mq)
      #pragma unroll
      for (int m = 0; m < 2; ++m)
        #pragma unroll
        for (int j = 0; j < 4; ++j, ++rr) {
          const int row = R + mq * 128 + qwr * 32 + m * 16 + q * 4 + j;
          part[(size_t)row * NPART + bn * 2 + qwc] = make_float2(bestv[rr], besti[rr]);
        }
  }
}

// ---------- final: per-row reduce of 64 partials, write index, gather code row ----------
__global__ __launch_bounds__(64)
void reduce_gather_kernel(const float2* __restrict__ part, const float* __restrict__ embed,
                          float* __restrict__ quant, float* __restrict__ ind)
{
  const int row = blockIdx.x;
  const int l = threadIdx.x;
  float2 a = part[(size_t)row * NPART + l];
  float bv = a.x, bi = a.y;
  #pragma unroll
  for (int m = 1; m < 64; m <<= 1) {
    float ov = __shfl_xor(bv, m);
    float oi = __shfl_xor(bi, m);
    if (ov > bv || (ov == bv && oi < bi)) { bv = ov; bi = oi; }
  }
  if (l == 0) ind[row] = bi;
  const int idx = (int)bi;
  const float4* src = reinterpret_cast<const float4*>(embed + (size_t)idx * DDIM);
  float4* dst = reinterpret_cast<float4*>(quant + (size_t)row * DDIM);
  dst[l]      = src[l];
  dst[l + 64] = src[l + 64];
}

extern "C" void kernel_launch(void* const* d_in, const int* in_sizes, int n_in,
                              void* d_out, int out_size, void* d_ws, size_t ws_size,
                              hipStream_t stream) {
  const float* x     = (const float*)d_in[0];
  const float* embed = (const float*)d_in[1];

  char* ws = (char*)d_ws;
  _Float16* xh = (_Float16*)(ws + WS_XH);
  _Float16* xl = (_Float16*)(ws + WS_XL);
  _Float16* eh = (_Float16*)(ws + WS_EH);
  _Float16* el = (_Float16*)(ws + WS_EL);
  float*    x2 = (float*)(ws + WS_X2);
  float*    e2 = (float*)(ws + WS_E2);
  float2*   part = (float2*)(ws + WS_PART);

  float* quant = (float*)d_out;
  float* ind   = (float*)d_out + OFF_IND;
  float* dist  = (float*)d_out + OFF_DIST;

  prep_kernel<<<dim3(NROWS + NCODE), 128, 0, stream>>>(x, embed, xh, xl, eh, el, x2, e2);
  dist_gemm_kernel<<<dim3(NBM * NBN), 512, 0, stream>>>(xh, xl, eh, el, x2, e2, dist, part);
  reduce_gather_kernel<<<dim3(NROWS), 64, 0, stream>>>(part, embed, quant, ind);
}